// Round 10
// baseline (232.645 us; speedup 1.0000x reference)
//
#include <hip/hip_runtime.h>
#include <stdint.h>

// ---------------- types ----------------
typedef short bf16x8 __attribute__((ext_vector_type(8)));
typedef float f32x4  __attribute__((ext_vector_type(4)));

__device__ __forceinline__ uint16_t f2bf(float f) {
    uint32_t u = __float_as_uint(f);
    u += 0x7FFF + ((u >> 16) & 1);   // round-to-nearest-even
    return (uint16_t)(u >> 16);
}
__device__ __forceinline__ uint32_t pk2bf(float a, float b) {
    return (uint32_t)f2bf(a) | ((uint32_t)f2bf(b) << 16);
}

typedef __attribute__((address_space(1))) const uint32_t gu32;
typedef __attribute__((address_space(3))) uint32_t lu32;
__device__ __forceinline__ void gload16(const void* g, void* l) {
    // async global->LDS, 16B/lane; LDS dest = wave-uniform base + lane*16 (m104/m108)
    __builtin_amdgcn_global_load_lds((gu32*)g, (lu32*)l, 16, 0, 0);
}

// ---------------- prologue: fp32 -> bf16 transposed weights ----------------
__global__ void transpose_bf16(const float* __restrict__ in, uint16_t* __restrict__ out,
                               int R, int C) {
    __shared__ float t[32][33];
    const int tx = threadIdx.x, ty = threadIdx.y;
    const int r0 = blockIdx.y * 32, c0 = blockIdx.x * 32;
    const float* ine = in + (size_t)blockIdx.z * R * C;
    uint16_t* oute   = out + (size_t)blockIdx.z * R * C;
#pragma unroll
    for (int j = 0; j < 4; ++j)
        t[ty + 8 * j][tx] = ine[(size_t)(r0 + ty + 8 * j) * C + (c0 + tx)];
    __syncthreads();
#pragma unroll
    for (int j = 0; j < 4; ++j) {
        int orow = c0 + ty + 8 * j;
        int ocol = r0 + tx;
        oute[(size_t)orow * R + ocol] = f2bf(t[tx][ty + 8 * j]);
    }
}

__global__ void cvt_bf16(const float* __restrict__ in, uint16_t* __restrict__ out, int n4) {
    const int i = blockIdx.x * blockDim.x + threadIdx.x;
    if (i < n4) {
        const float4 v = ((const float4*)in)[i];
        ushort4 h;
        h.x = f2bf(v.x); h.y = f2bf(v.y); h.z = f2bf(v.z); h.w = f2bf(v.w);
        ((ushort4*)out)[i] = h;
    }
}

// =====================================================================
// Layer 1: 256x256 tile, BK=64, 8 waves, 2-phase counted-vmcnt schedule
// (round-8/9 verified). Both-sides 16B-slot XOR swizzle (r7: conflicts=0).
// Swapped MFMA: D = mfma(A=W frag [n][k], B=act frag [m][k])
//   -> D col(lane&15)=batch row, row(kg*4+v)=out col.
// =====================================================================
template <int K>
__global__ __launch_bounds__(512, 1) void gemm256(
    const uint16_t* __restrict__ Act,   // activations, + e*actEStride, [Mc][K]
    size_t actEStride,                  // 0 when shared across e (layer 1)
    const uint16_t* __restrict__ Wt,    // [8][512][K] bf16 (n-major, k-contig)
    const float* __restrict__ bias,     // [8][512]
    uint16_t* __restrict__ Out,         // + e*outEStride, [Mc][512] bf16 (relu'd)
    size_t outEStride)
{
    extern __shared__ char smem[];      // 2 x 64KB: [W 32K | Act 32K]
    const int tid = threadIdx.x, wid = tid >> 6, lane = tid & 63;
    const int kg = lane >> 4, lr = lane & 15;
    const int e   = blockIdx.x;
    const int nb0 = blockIdx.y * 256;
    const int m0  = blockIdx.z * 256;
    const int wm = wid >> 2, wn = wid & 3;

    const uint16_t* Wbase = Wt  + ((size_t)e * 512 + nb0) * K;
    const uint16_t* Abase = Act + (size_t)e * actEStride + (size_t)m0 * K;
    uint16_t* Obase       = Out + (size_t)e * outEStride;

    f32x4 acc[8][4];
#pragma unroll
    for (int b = 0; b < 8; ++b)
#pragma unroll
        for (int c = 0; c < 4; ++c) acc[b][c] = f32x4{0.f, 0.f, 0.f, 0.f};

    const int rlo = lane >> 3, pslot = lane & 7;   // staging lane map
    const int lswz = (pslot ^ rlo) * 8;            // pre-swizzled source k-offset

    auto STAGE = [&](int p, int ks) {
#pragma unroll
        for (int g = 0; g < 4; ++g) {
            const int row = g * 64 + wid * 8 + rlo;    // row&7 == rlo
            gload16(Wbase + (size_t)row * K + ks + lswz,
                    smem + p * 65536 + g * 8192 + wid * 1024);
        }
#pragma unroll
        for (int g = 0; g < 4; ++g) {
            const int row = g * 64 + wid * 8 + rlo;
            gload16(Abase + (size_t)row * K + ks + lswz,
                    smem + p * 65536 + 32768 + g * 8192 + wid * 1024);
        }
    };

    constexpr int NT = K / 64;
    STAGE(0, 0);

#pragma unroll
    for (int t = 0; t < NT; ++t) {
        const int cur = t & 1;
        if (t + 1 < NT) {
            STAGE(1 - cur, (t + 1) * 64);
            asm volatile("s_waitcnt vmcnt(8)" ::: "memory");   // tile t landed
        } else {
            asm volatile("s_waitcnt vmcnt(0)" ::: "memory");
        }
        __builtin_amdgcn_s_barrier();
        asm volatile("" ::: "memory");

        const char* sW = smem + cur * 65536;
        const char* sA = sW + 32768;
#pragma unroll
        for (int kh = 0; kh < 2; ++kh) {
            bf16x8 wf[4], af[8];
#pragma unroll
            for (int c = 0; c < 4; ++c) {
                const int row = wn * 64 + c * 16 + lr;
                wf[c] = *(const bf16x8*)(sW + row * 128 +
                                         (((kh * 4 + kg) ^ (row & 7)) << 4));
            }
#pragma unroll
            for (int b = 0; b < 8; ++b) {
                const int row = wm * 128 + b * 16 + lr;
                af[b] = *(const bf16x8*)(sA + row * 128 +
                                         (((kh * 4 + kg) ^ (row & 7)) << 4));
            }
#pragma unroll
            for (int b = 0; b < 8; ++b)
#pragma unroll
                for (int c = 0; c < 4; ++c)
                    acc[b][c] = __builtin_amdgcn_mfma_f32_16x16x32_bf16(wf[c], af[b], acc[b][c], 0, 0, 0);
        }
        asm volatile("s_waitcnt lgkmcnt(0)" ::: "memory");
        __builtin_amdgcn_s_barrier();
        asm volatile("" ::: "memory");
    }

    // epilogue: bias + relu -> bf16, 8B stores, row-contiguous
#pragma unroll
    for (int c = 0; c < 4; ++c) {
        const int col = nb0 + wn * 64 + c * 16 + kg * 4;
        const float4 bv = *(const float4*)(bias + e * 512 + col);
#pragma unroll
        for (int b = 0; b < 8; ++b) {
            const float x0 = fmaxf(acc[b][c][0] + bv.x, 0.f);
            const float x1 = fmaxf(acc[b][c][1] + bv.y, 0.f);
            const float x2 = fmaxf(acc[b][c][2] + bv.z, 0.f);
            const float x3 = fmaxf(acc[b][c][3] + bv.w, 0.f);
            uint2 w;
            w.x = pk2bf(x0, x1);
            w.y = pk2bf(x2, x3);
            const int row = m0 + wm * 128 + b * 16 + lr;
            *(uint2*)(Obase + (size_t)row * 512 + col) = w;
        }
    }
}

// =====================================================================
// Fused layers 2+3: per block = 256 batch rows x one e; out[256][32].
// Two n-half passes; each = verified gemm256<512> 2-phase K-loop over
// W2[half*256..+256), then h2half (bias+relu, bf16) written into the
// DRAINED staging LDS (128KB, swizzled), barrier, L3 partial-accumulate
// out += h2half @ W3[:, half*256..+256) with W3 frags from global (L2).
// h2 never touches HBM. Counted-vmcnt safety: stray VMEM (bias/W3) only
// makes the vmcnt(8) gate stricter (oldest-retire-first).
// =====================================================================
__global__ __launch_bounds__(512, 1) void gemm_l23(
    const uint16_t* __restrict__ H1,    // + e*h1EStride, [Mc][512]
    size_t h1EStride,
    const uint16_t* __restrict__ W2t,   // [8][512][512] bf16 (n-major, k-contig)
    const float* __restrict__ b2,       // [8][512]
    const uint16_t* __restrict__ W3t,   // [8][32][512]  bf16 (o-major, k-contig)
    const float* __restrict__ b3,       // [8][32]
    float* __restrict__ Out)            // chunk base of [B][256] fp32
{
    extern __shared__ char smem[];      // 128KB staging / h2half[256][256] bf16
    const int tid = threadIdx.x, wid = tid >> 6, lane = tid & 63;
    const int kg = lane >> 4, lr = lane & 15;
    const int e  = blockIdx.x;
    const int m0 = blockIdx.z * 256;
    const int wm = wid >> 2, wn = wid & 3;

    const uint16_t* Abase = H1 + (size_t)e * h1EStride + (size_t)m0 * 512;
    const uint16_t* W3e   = W3t + (size_t)e * 32 * 512;

    const int rlo = lane >> 3, pslot = lane & 7;
    const int lswz = (pslot ^ rlo) * 8;

    f32x4 oacc[2][2];                    // out acc [m-frag][o-frag], persists
#pragma unroll
    for (int i = 0; i < 2; ++i)
#pragma unroll
        for (int j = 0; j < 2; ++j) oacc[i][j] = f32x4{0.f, 0.f, 0.f, 0.f};

    for (int half = 0; half < 2; ++half) {
        const uint16_t* Wbase = W2t + ((size_t)e * 512 + half * 256) * 512;

        f32x4 acc[8][4];
#pragma unroll
        for (int b = 0; b < 8; ++b)
#pragma unroll
            for (int c = 0; c < 4; ++c) acc[b][c] = f32x4{0.f, 0.f, 0.f, 0.f};

        auto STAGE = [&](int p, int ks) {
#pragma unroll
            for (int g = 0; g < 4; ++g) {
                const int row = g * 64 + wid * 8 + rlo;
                gload16(Wbase + (size_t)row * 512 + ks + lswz,
                        smem + p * 65536 + g * 8192 + wid * 1024);
            }
#pragma unroll
            for (int g = 0; g < 4; ++g) {
                const int row = g * 64 + wid * 8 + rlo;
                gload16(Abase + (size_t)row * 512 + ks + lswz,
                        smem + p * 65536 + 32768 + g * 8192 + wid * 1024);
            }
        };

        STAGE(0, 0);
#pragma unroll
        for (int t = 0; t < 8; ++t) {
            const int cur = t & 1;
            if (t + 1 < 8) {
                STAGE(1 - cur, (t + 1) * 64);
                asm volatile("s_waitcnt vmcnt(8)" ::: "memory");
            } else {
                asm volatile("s_waitcnt vmcnt(0)" ::: "memory");   // drain: LDS free after
            }
            __builtin_amdgcn_s_barrier();
            asm volatile("" ::: "memory");

            const char* sW = smem + cur * 65536;
            const char* sA = sW + 32768;
#pragma unroll
            for (int kh = 0; kh < 2; ++kh) {
                bf16x8 wf[4], af[8];
#pragma unroll
                for (int c = 0; c < 4; ++c) {
                    const int row = wn * 64 + c * 16 + lr;
                    wf[c] = *(const bf16x8*)(sW + row * 128 +
                                             (((kh * 4 + kg) ^ (row & 7)) << 4));
                }
#pragma unroll
                for (int b = 0; b < 8; ++b) {
                    const int row = wm * 128 + b * 16 + lr;
                    af[b] = *(const bf16x8*)(sA + row * 128 +
                                             (((kh * 4 + kg) ^ (row & 7)) << 4));
                }
#pragma unroll
                for (int b = 0; b < 8; ++b)
#pragma unroll
                    for (int c = 0; c < 4; ++c)
                        acc[b][c] = __builtin_amdgcn_mfma_f32_16x16x32_bf16(wf[c], af[b], acc[b][c], 0, 0, 0);
            }
            asm volatile("s_waitcnt lgkmcnt(0)" ::: "memory");
            __builtin_amdgcn_s_barrier();
            asm volatile("" ::: "memory");
        }
        // staging fully drained (vmcnt(0) + barriers) -> smem reusable as h2half

        // ---- epilogue: bias+relu -> bf16 h2half[256 m][256 k'] swizzled ----
#pragma unroll
        for (int c = 0; c < 4; ++c) {
            const int coll = wn * 64 + c * 16 + kg * 4;   // local n (= L3 k) 0..255
            const float4 bv = *(const float4*)(b2 + e * 512 + half * 256 + coll);
#pragma unroll
            for (int b = 0; b < 8; ++b) {
                const float x0 = fmaxf(acc[b][c][0] + bv.x, 0.f);
                const float x1 = fmaxf(acc[b][c][1] + bv.y, 0.f);
                const float x2 = fmaxf(acc[b][c][2] + bv.z, 0.f);
                const float x3 = fmaxf(acc[b][c][3] + bv.w, 0.f);
                uint2 w;
                w.x = pk2bf(x0, x1);
                w.y = pk2bf(x2, x3);
                const int row = wm * 128 + b * 16 + lr;   // m-row 0..255
                *(uint2*)(smem + row * 512 + ((coll * 2) ^ ((row & 7) << 4))) = w;
            }
        }
        __syncthreads();   // h2half visible to all waves

        // ---- L3 partial: out += h2half @ W3[:, half*256..+256) ----
        // wave owns 32 m-rows [wid*32, wid*32+32); o = all 32 cols.
        // swapped MFMA: D=mfma(A=W3 frag [o][k], B=h2 frag [m][k])
        //   -> col(lane&15)=m-row, row(kg*4+v)=o-col.
#pragma unroll
        for (int mf = 0; mf < 2; ++mf)
#pragma unroll
            for (int kc = 0; kc < 8; ++kc) {
                const int row = wid * 32 + mf * 16 + lr;
                const bf16x8 hb = *(const bf16x8*)(smem + row * 512 +
                                                   (((kc * 4 + kg) << 4) ^ ((row & 7) << 4)));
#pragma unroll
                for (int of = 0; of < 2; ++of) {
                    const bf16x8 wf = *(const bf16x8*)(W3e + (size_t)(of * 16 + lr) * 512 +
                                                       half * 256 + kc * 32 + kg * 8);
                    oacc[mf][of] = __builtin_amdgcn_mfma_f32_16x16x32_bf16(wf, hb, oacc[mf][of], 0, 0, 0);
                }
            }
        __syncthreads();   // h2half consumed; safe to re-stage next half
    }

    // ---- final store: bias3 + float4, row-contiguous ----
#pragma unroll
    for (int mf = 0; mf < 2; ++mf)
#pragma unroll
        for (int of = 0; of < 2; ++of) {
            const int col = e * 32 + of * 16 + kg * 4;
            const float4 bv = *(const float4*)(b3 + col);
            const int row = m0 + wid * 32 + mf * 16 + lr;
            float4 res;
            res.x = oacc[mf][of][0] + bv.x;
            res.y = oacc[mf][of][1] + bv.y;
            res.z = oacc[mf][of][2] + bv.z;
            res.w = oacc[mf][of][3] + bv.w;
            *(float4*)(Out + (size_t)row * 256 + col) = res;
        }
}

// =====================================================================
// Fallback (round-3 fused kernel, 14.25MB ws) — only if ws too small.
// =====================================================================
template <int K, bool B_LDS>
__device__ __forceinline__ void layer128(
    const uint16_t* __restrict__ Aw, const uint16_t* __restrict__ Bg,
    const char* __restrict__ Bl, const float* __restrict__ bias,
    char* __restrict__ ldsOut, int n0, int kg, int lr, bool syncBeforeEpi) {
    f32x4 acc[8][4];
#pragma unroll
    for (int m = 0; m < 8; ++m)
#pragma unroll
        for (int n = 0; n < 4; ++n) acc[m][n] = f32x4{0.f, 0.f, 0.f, 0.f};
    auto ldA = [&](int mf, int k0) -> bf16x8 {
        return *(const bf16x8*)(Aw + (size_t)(mf * 16 + lr) * K + k0 + kg * 8);
    };
    auto ldB = [&](int nf, int k0) -> bf16x8 {
        if constexpr (B_LDS) {
            const int row = nf * 16 + lr;
            return *(const bf16x8*)(Bl + row * 1024 +
                                    ((((k0 + kg * 8) << 1)) ^ ((row & 7) << 4)));
        } else {
            return *(const bf16x8*)(Bg + (size_t)(nf * 16 + lr) * K + k0 + kg * 8);
        }
    };
    bf16x8 a0[8], b0[4], a1[8], b1[4];
#pragma unroll
    for (int i = 0; i < 8; ++i) a0[i] = ldA(i, 0);
#pragma unroll
    for (int i = 0; i < 4; ++i) b0[i] = ldB(i, 0);
#pragma unroll
    for (int k0 = 0; k0 < K; k0 += 64) {
#pragma unroll
        for (int i = 0; i < 8; ++i) a1[i] = ldA(i, k0 + 32);
#pragma unroll
        for (int i = 0; i < 4; ++i) b1[i] = ldB(i, k0 + 32);
#pragma unroll
        for (int m = 0; m < 8; ++m)
#pragma unroll
            for (int n = 0; n < 4; ++n)
                acc[m][n] = __builtin_amdgcn_mfma_f32_16x16x32_bf16(a0[m], b0[n], acc[m][n], 0, 0, 0);
        if (k0 + 64 < K) {
#pragma unroll
            for (int i = 0; i < 8; ++i) a0[i] = ldA(i, k0 + 64);
#pragma unroll
            for (int i = 0; i < 4; ++i) b0[i] = ldB(i, k0 + 64);
        }
#pragma unroll
        for (int m = 0; m < 8; ++m)
#pragma unroll
            for (int n = 0; n < 4; ++n)
                acc[m][n] = __builtin_amdgcn_mfma_f32_16x16x32_bf16(a1[m], b1[n], acc[m][n], 0, 0, 0);
    }
    if (syncBeforeEpi) __syncthreads();
#pragma unroll
    for (int mf = 0; mf < 8; ++mf) {
        const float4 bv = *(const float4*)(bias + mf * 16 + kg * 4);
#pragma unroll
        for (int nf = 0; nf < 4; ++nf) {
            float x0 = fmaxf(acc[mf][nf][0] + bv.x, 0.f);
            float x1 = fmaxf(acc[mf][nf][1] + bv.y, 0.f);
            float x2 = fmaxf(acc[mf][nf][2] + bv.z, 0.f);
            float x3 = fmaxf(acc[mf][nf][3] + bv.w, 0.f);
            uint2 w;
            w.x = pk2bf(x0, x1);
            w.y = pk2bf(x2, x3);
            const int row = nf * 16 + lr;
            const int colbyte = (n0 + mf * 16 + kg * 4) << 1;
            *(uint2*)(ldsOut + row * 1024 + (colbyte ^ ((row & 7) << 4))) = w;
        }
    }
}

__global__ __launch_bounds__(256, 2) void fused_mlp(
    const uint16_t* __restrict__ Xbf,
    const uint16_t* __restrict__ W1T, const float* __restrict__ b1,
    const uint16_t* __restrict__ W2T, const float* __restrict__ b2,
    const uint16_t* __restrict__ W3T, const float* __restrict__ b3,
    float* __restrict__ out) {
    extern __shared__ char hbuf[];
    const int tid = threadIdx.x, wid = tid >> 6, lane = tid & 63;
    const int kg = lane >> 4, lr = lane & 15;
    const int e  = blockIdx.x & 7;
    const int b0 = (blockIdx.x >> 3) * 64;
    const int n0 = wid * 128;
    layer128<256, false>(W1T + ((size_t)e * 512 + n0) * 256, Xbf + (size_t)b0 * 256,
                         nullptr, b1 + e * 512 + n0, hbuf, n0, kg, lr, false);
    __syncthreads();
    layer128<512, true>(W2T + ((size_t)e * 512 + n0) * 512, nullptr, hbuf,
                        b2 + e * 512 + n0, hbuf, n0, kg, lr, true);
    __syncthreads();
    {
        const int rowB  = wid * 16 + lr;
        const int bbyte = rowB * 1024;
        const int bswz  = (rowB & 7) << 4;
        const uint16_t* W3e = W3T + (size_t)e * 32 * 512;
        f32x4 acc[2];
        acc[0] = f32x4{0.f, 0.f, 0.f, 0.f};
        acc[1] = f32x4{0.f, 0.f, 0.f, 0.f};
#pragma unroll
        for (int k0 = 0; k0 < 512; k0 += 32) {
            bf16x8 a = *(const bf16x8*)(hbuf + bbyte + ((((k0 + kg * 8) << 1)) ^ bswz));
#pragma unroll
            for (int nf = 0; nf < 2; ++nf) {
                bf16x8 b = *(const bf16x8*)(W3e + (size_t)(nf * 16 + lr) * 512 + k0 + kg * 8);
                acc[nf] = __builtin_amdgcn_mfma_f32_16x16x32_bf16(a, b, acc[nf], 0, 0, 0);
            }
        }
#pragma unroll
        for (int nf = 0; nf < 2; ++nf) {
            const float bb = b3[e * 32 + nf * 16 + lr];
#pragma unroll
            for (int v = 0; v < 4; ++v) {
                const int row = b0 + wid * 16 + kg * 4 + v;
                out[(size_t)row * 256 + e * 32 + nf * 16 + lr] = acc[nf][v] + bb;
            }
        }
    }
}

// ---------------- host launch ----------------
extern "C" void kernel_launch(void* const* d_in, const int* in_sizes, int n_in,
                              void* d_out, int out_size, void* d_ws, size_t ws_size,
                              hipStream_t stream) {
    (void)in_sizes; (void)n_in; (void)out_size;
    const float* X  = (const float*)d_in[0];   // [16384,256]
    const float* W1 = (const float*)d_in[1];   // [8,256,512]
    const float* b1 = (const float*)d_in[2];   // [8,512]
    const float* W2 = (const float*)d_in[3];   // [8,512,512]
    const float* b2 = (const float*)d_in[4];   // [8,512]
    const float* W3 = (const float*)d_in[5];   // [8,512,32]
    const float* b3 = (const float*)d_in[6];   // [8,32]
    float* out = (float*)d_out;                // [16384,8,32]

    uint16_t* w1t = (uint16_t*)d_ws;           // [8][512][256] bf16  (2 MB)
    uint16_t* w2t = w1t + 8 * 256 * 512;       // [8][512][512] bf16  (4 MB)
    uint16_t* w3t = w2t + 8 * 512 * 512;       // [8][32][512]  bf16  (256 KB)
    uint16_t* xbf = w3t + 8 * 512 * 32;        // [16384][256]  bf16  (8 MB)
    uint16_t* h1  = xbf + (size_t)16384 * 256; // [8][Mc][512] bf16, e-major
    const size_t FIXED_BYTES = ((size_t)(8 * 256 * 512) + 8 * 512 * 512 + 8 * 32 * 512 +
                                (size_t)16384 * 256) * 2;   // 14,942,208

    // largest chunk whose e-indexed h1 fits the workspace (h2 eliminated)
    int Mc = 0;
    for (int cand = 16384; cand >= 2048; cand >>= 1) {
        if (ws_size >= FIXED_BYTES + (size_t)8192 * cand) { Mc = cand; break; }
    }

    dim3 blk(32, 8);
    transpose_bf16<<<dim3(512 / 32, 256 / 32, 8), blk, 0, stream>>>(W1, w1t, 256, 512);
    transpose_bf16<<<dim3(512 / 32, 512 / 32, 8), blk, 0, stream>>>(W2, w2t, 512, 512);
    transpose_bf16<<<dim3(32 / 32, 512 / 32, 8),  blk, 0, stream>>>(W3, w3t, 512, 32);
    cvt_bf16<<<4096, 256, 0, stream>>>(X, xbf, 16384 * 256 / 4);

    if (Mc > 0) {
        const size_t eStr = (size_t)Mc * 512;
        (void)hipFuncSetAttribute((const void*)gemm256<256>,
                                  hipFuncAttributeMaxDynamicSharedMemorySize, 131072);
        (void)hipFuncSetAttribute((const void*)gemm_l23,
                                  hipFuncAttributeMaxDynamicSharedMemorySize, 131072);
        for (int c0 = 0; c0 < 16384; c0 += Mc) {
            gemm256<256><<<dim3(8, 2, Mc / 256), 512, 131072, stream>>>(
                xbf + (size_t)c0 * 256, 0, w1t, b1, h1, eStr);
            gemm_l23<<<dim3(8, 1, Mc / 256), 512, 131072, stream>>>(
                h1, eStr, w2t, b2, w3t, b3, out + (size_t)c0 * 256);
        }
    } else {
        (void)hipFuncSetAttribute((const void*)fused_mlp,
                                  hipFuncAttributeMaxDynamicSharedMemorySize, 65536);
        fused_mlp<<<2048, 256, 65536, stream>>>(xbf, w1t, b1, w2t, b2, w3t, b3, out);
    }
}

// Round 12
// 208.641 us; speedup vs baseline: 1.1151x; 1.1151x over previous
//
#include <hip/hip_runtime.h>
#include <stdint.h>

// ---------------- types ----------------
typedef short bf16x8 __attribute__((ext_vector_type(8)));
typedef float f32x4  __attribute__((ext_vector_type(4)));

__device__ __forceinline__ uint16_t f2bf(float f) {
    uint32_t u = __float_as_uint(f);
    u += 0x7FFF + ((u >> 16) & 1);   // round-to-nearest-even
    return (uint16_t)(u >> 16);
}
__device__ __forceinline__ uint32_t pk2bf(float a, float b) {
    return (uint32_t)f2bf(a) | ((uint32_t)f2bf(b) << 16);
}

typedef __attribute__((address_space(1))) const uint32_t gu32;
typedef __attribute__((address_space(3))) uint32_t lu32;
__device__ __forceinline__ void gload16(const void* g, void* l) {
    // async global->LDS, 16B/lane; LDS dest = wave-uniform base + lane*16 (m104/m108)
    __builtin_amdgcn_global_load_lds((gu32*)g, (lu32*)l, 16, 0, 0);
}

// ---------------- prologue: fp32 -> bf16 transposed weights ----------------
__global__ void transpose_bf16(const float* __restrict__ in, uint16_t* __restrict__ out,
                               int R, int C) {
    __shared__ float t[32][33];
    const int tx = threadIdx.x, ty = threadIdx.y;
    const int r0 = blockIdx.y * 32, c0 = blockIdx.x * 32;
    const float* ine = in + (size_t)blockIdx.z * R * C;
    uint16_t* oute   = out + (size_t)blockIdx.z * R * C;
#pragma unroll
    for (int j = 0; j < 4; ++j)
        t[ty + 8 * j][tx] = ine[(size_t)(r0 + ty + 8 * j) * C + (c0 + tx)];
    __syncthreads();
#pragma unroll
    for (int j = 0; j < 4; ++j) {
        int orow = c0 + ty + 8 * j;
        int ocol = r0 + tx;
        oute[(size_t)orow * R + ocol] = f2bf(t[tx][ty + 8 * j]);
    }
}

__global__ void cvt_bf16(const float* __restrict__ in, uint16_t* __restrict__ out, int n4) {
    const int i = blockIdx.x * blockDim.x + threadIdx.x;
    if (i < n4) {
        const float4 v = ((const float4*)in)[i];
        ushort4 h;
        h.x = f2bf(v.x); h.y = f2bf(v.y); h.z = f2bf(v.z); h.w = f2bf(v.w);
        ((ushort4*)out)[i] = h;
    }
}

// =====================================================================
// 256x256 tile, BK=64, 8 waves. Catalog-exact minimum 2-phase schedule:
//   prologue STAGE(0); sync;
//   loop t: { if t+1<NT: STAGE(next);   // issue BEFORE compute
//             compute buf[cur];         // ds_read+MFMA hides load latency
//             __syncthreads(); }        // full drain = the ONE gate/tile
// The drain waits only the RESIDUAL latency of the prefetch (issued a
// whole compute-phase earlier). r8-r11 gated right after issuing STAGE
// -> exposed a full L2/HBM round-trip per K-step (r9: ~9300cy/K-step).
// No counted vmcnt: r11 showed exact-count vmcnt(16) with global_load_lds
// is racy on this HW; __syncthreads' full drain is race-free.
// Both-sides 16B-slot XOR swizzle (r7-verified: conflicts == 0).
// Swapped MFMA: D = mfma(A=W frag [n][k], B=act frag [m][k])
//   -> D col(lane&15)=batch row, row(kg*4+v)=out col.
// =====================================================================
template <int K>
__global__ __launch_bounds__(512, 1) void gemm256(
    const uint16_t* __restrict__ Act,   // activations, + e*actEStride, [Mc][K]
    size_t actEStride,                  // 0 when shared across e (layer 1)
    const uint16_t* __restrict__ Wt,    // [8][512][K] bf16 (n-major, k-contig)
    const float* __restrict__ bias,     // [8][512]
    uint16_t* __restrict__ Out,         // + e*outEStride, [Mc][512] bf16 (relu'd)
    size_t outEStride)
{
    extern __shared__ char smem[];      // 2 x 64KB: [W 32K | Act 32K]
    const int tid = threadIdx.x, wid = tid >> 6, lane = tid & 63;
    const int kg = lane >> 4, lr = lane & 15;
    const int e   = blockIdx.x;
    const int nb0 = blockIdx.y * 256;
    const int m0  = blockIdx.z * 256;
    const int wm = wid >> 2, wn = wid & 3;

    const uint16_t* Wbase = Wt  + ((size_t)e * 512 + nb0) * K;
    const uint16_t* Abase = Act + (size_t)e * actEStride + (size_t)m0 * K;
    uint16_t* Obase       = Out + (size_t)e * outEStride;

    f32x4 acc[8][4];
#pragma unroll
    for (int b = 0; b < 8; ++b)
#pragma unroll
        for (int c = 0; c < 4; ++c) acc[b][c] = f32x4{0.f, 0.f, 0.f, 0.f};

    const int rlo = lane >> 3, pslot = lane & 7;   // staging lane map
    const int lswz = (pslot ^ rlo) * 8;            // pre-swizzled source k-offset

    auto STAGE = [&](int p, int ks) {
#pragma unroll
        for (int g = 0; g < 4; ++g) {
            const int row = g * 64 + wid * 8 + rlo;    // row&7 == rlo
            gload16(Wbase + (size_t)row * K + ks + lswz,
                    smem + p * 65536 + g * 8192 + wid * 1024);
        }
#pragma unroll
        for (int g = 0; g < 4; ++g) {
            const int row = g * 64 + wid * 8 + rlo;
            gload16(Abase + (size_t)row * K + ks + lswz,
                    smem + p * 65536 + 32768 + g * 8192 + wid * 1024);
        }
    };

    constexpr int NT = K / 64;
    STAGE(0, 0);
    __syncthreads();                     // tile 0 in LDS

#pragma unroll
    for (int t = 0; t < NT; ++t) {
        const int cur = t & 1;
        if (t + 1 < NT)
            STAGE(1 - cur, (t + 1) * 64);        // issue prefetch BEFORE compute
        asm volatile("" ::: "memory");           // pin issue order: STAGE above compute

        const char* sW = smem + cur * 65536;
        const char* sA = sW + 32768;
        __builtin_amdgcn_s_setprio(1);
#pragma unroll
        for (int kh = 0; kh < 2; ++kh) {
            bf16x8 wf[4], af[8];
#pragma unroll
            for (int c = 0; c < 4; ++c) {
                const int row = wn * 64 + c * 16 + lr;
                wf[c] = *(const bf16x8*)(sW + row * 128 +
                                         (((kh * 4 + kg) ^ (row & 7)) << 4));
            }
#pragma unroll
            for (int b = 0; b < 8; ++b) {
                const int row = wm * 128 + b * 16 + lr;
                af[b] = *(const bf16x8*)(sA + row * 128 +
                                         (((kh * 4 + kg) ^ (row & 7)) << 4));
            }
#pragma unroll
            for (int b = 0; b < 8; ++b)
#pragma unroll
                for (int c = 0; c < 4; ++c)
                    acc[b][c] = __builtin_amdgcn_mfma_f32_16x16x32_bf16(wf[c], af[b], acc[b][c], 0, 0, 0);
        }
        __builtin_amdgcn_s_setprio(0);
        __syncthreads();   // ONE gate/tile: drains prefetch residual latency + reads
    }

    // epilogue: bias + relu -> bf16, 8B stores, row-contiguous
#pragma unroll
    for (int c = 0; c < 4; ++c) {
        const int col = nb0 + wn * 64 + c * 16 + kg * 4;
        const float4 bv = *(const float4*)(bias + e * 512 + col);
#pragma unroll
        for (int b = 0; b < 8; ++b) {
            const float x0 = fmaxf(acc[b][c][0] + bv.x, 0.f);
            const float x1 = fmaxf(acc[b][c][1] + bv.y, 0.f);
            const float x2 = fmaxf(acc[b][c][2] + bv.z, 0.f);
            const float x3 = fmaxf(acc[b][c][3] + bv.w, 0.f);
            uint2 w;
            w.x = pk2bf(x0, x1);
            w.y = pk2bf(x2, x3);
            const int row = m0 + wm * 128 + b * 16 + lr;
            *(uint2*)(Obase + (size_t)row * 512 + col) = w;
        }
    }
}

// ---- layer 3: Mc x 32, K=512; same catalog 2-phase recipe ----
__global__ __launch_bounds__(256, 4) void gemm_o(
    const uint16_t* __restrict__ Act,   // h2, + e*actEStride, [Mc][512]
    size_t actEStride,
    const uint16_t* __restrict__ W3t,   // [8][32][512] bf16
    const float* __restrict__ b3,       // [8][32]
    float* __restrict__ Out)            // chunk base of [B][256] fp32 (= [B][E][32])
{
    __shared__ char smem[40960];        // 2 phases x 20KB: [Act 16K | W3 4K]
    const int tid = threadIdx.x, wid = tid >> 6, lane = tid & 63;
    const int kg = lane >> 4, lr = lane & 15;
    const int e  = blockIdx.x;
    const int m0 = blockIdx.z * 128;

    const uint16_t* Abase = Act + (size_t)e * actEStride + (size_t)m0 * 512;
    const uint16_t* Bbase = W3t + (size_t)e * 32 * 512;

    f32x4 acc[2][2];
#pragma unroll
    for (int i = 0; i < 2; ++i)
#pragma unroll
        for (int j = 0; j < 2; ++j) acc[i][j] = f32x4{0.f, 0.f, 0.f, 0.f};

    const int rlo = lane >> 3, pslot = lane & 7;
    const int lswz = (pslot ^ rlo) * 8;

    auto STAGE = [&](int p, int ks) {
#pragma unroll
        for (int i = 0; i < 4; ++i) {
            const int g   = wid * 4 + i;
            const int row = g * 8 + rlo;
            gload16(Abase + (size_t)row * 512 + ks + lswz, smem + p * 20480 + g * 1024);
        }
        const int row = wid * 8 + rlo;
        gload16(Bbase + (size_t)row * 512 + ks + lswz, smem + p * 20480 + 16384 + wid * 1024);
    };

    STAGE(0, 0);
    __syncthreads();

#pragma unroll
    for (int t = 0; t < 8; ++t) {
        const int cur = t & 1;
        if (t + 1 < 8)
            STAGE(1 - cur, (t + 1) * 64);
        asm volatile("" ::: "memory");

        const char* sA = smem + cur * 20480;
        const char* sB = sA + 16384;
        __builtin_amdgcn_s_setprio(1);
#pragma unroll
        for (int h = 0; h < 2; ++h) {
            bf16x8 a[2], b[2];
#pragma unroll
            for (int i = 0; i < 2; ++i) {
                const int rowA = wid * 32 + i * 16 + lr;   // wave owns 32 batch rows
                a[i] = *(const bf16x8*)(sA + rowA * 128 +
                                        (((4 * h + kg) ^ (rowA & 7)) << 4));
                const int rowB = i * 16 + lr;
                b[i] = *(const bf16x8*)(sB + rowB * 128 +
                                        (((4 * h + kg) ^ (rowB & 7)) << 4));
            }
#pragma unroll
            for (int af = 0; af < 2; ++af)
#pragma unroll
                for (int bf = 0; bf < 2; ++bf)
                    acc[af][bf] = __builtin_amdgcn_mfma_f32_16x16x32_bf16(a[af], b[bf], acc[af][bf], 0, 0, 0);
        }
        __builtin_amdgcn_s_setprio(0);
        __syncthreads();
    }

#pragma unroll
    for (int af = 0; af < 2; ++af)
#pragma unroll
        for (int bf = 0; bf < 2; ++bf) {
            const float bb = b3[e * 32 + bf * 16 + lr];
#pragma unroll
            for (int v = 0; v < 4; ++v) {
                const int row = m0 + wid * 32 + af * 16 + kg * 4 + v;
                Out[(size_t)row * 256 + e * 32 + bf * 16 + lr] = acc[af][bf][v] + bb;
            }
        }
}

// =====================================================================
// Fallback (round-3 fused kernel, 14.25MB ws) — only if ws too small.
// =====================================================================
template <int K, bool B_LDS>
__device__ __forceinline__ void layer128(
    const uint16_t* __restrict__ Aw, const uint16_t* __restrict__ Bg,
    const char* __restrict__ Bl, const float* __restrict__ bias,
    char* __restrict__ ldsOut, int n0, int kg, int lr, bool syncBeforeEpi) {
    f32x4 acc[8][4];
#pragma unroll
    for (int m = 0; m < 8; ++m)
#pragma unroll
        for (int n = 0; n < 4; ++n) acc[m][n] = f32x4{0.f, 0.f, 0.f, 0.f};
    auto ldA = [&](int mf, int k0) -> bf16x8 {
        return *(const bf16x8*)(Aw + (size_t)(mf * 16 + lr) * K + k0 + kg * 8);
    };
    auto ldB = [&](int nf, int k0) -> bf16x8 {
        if constexpr (B_LDS) {
            const int row = nf * 16 + lr;
            return *(const bf16x8*)(Bl + row * 1024 +
                                    ((((k0 + kg * 8) << 1)) ^ ((row & 7) << 4)));
        } else {
            return *(const bf16x8*)(Bg + (size_t)(nf * 16 + lr) * K + k0 + kg * 8);
        }
    };
    bf16x8 a0[8], b0[4], a1[8], b1[4];
#pragma unroll
    for (int i = 0; i < 8; ++i) a0[i] = ldA(i, 0);
#pragma unroll
    for (int i = 0; i < 4; ++i) b0[i] = ldB(i, 0);
#pragma unroll
    for (int k0 = 0; k0 < K; k0 += 64) {
#pragma unroll
        for (int i = 0; i < 8; ++i) a1[i] = ldA(i, k0 + 32);
#pragma unroll
        for (int i = 0; i < 4; ++i) b1[i] = ldB(i, k0 + 32);
#pragma unroll
        for (int m = 0; m < 8; ++m)
#pragma unroll
            for (int n = 0; n < 4; ++n)
                acc[m][n] = __builtin_amdgcn_mfma_f32_16x16x32_bf16(a0[m], b0[n], acc[m][n], 0, 0, 0);
        if (k0 + 64 < K) {
#pragma unroll
            for (int i = 0; i < 8; ++i) a0[i] = ldA(i, k0 + 64);
#pragma unroll
            for (int i = 0; i < 4; ++i) b0[i] = ldB(i, k0 + 64);
        }
#pragma unroll
        for (int m = 0; m < 8; ++m)
#pragma unroll
            for (int n = 0; n < 4; ++n)
                acc[m][n] = __builtin_amdgcn_mfma_f32_16x16x32_bf16(a1[m], b1[n], acc[m][n], 0, 0, 0);
    }
    if (syncBeforeEpi) __syncthreads();
#pragma unroll
    for (int mf = 0; mf < 8; ++mf) {
        const float4 bv = *(const float4*)(bias + mf * 16 + kg * 4);
#pragma unroll
        for (int nf = 0; nf < 4; ++nf) {
            float x0 = fmaxf(acc[mf][nf][0] + bv.x, 0.f);
            float x1 = fmaxf(acc[mf][nf][1] + bv.y, 0.f);
            float x2 = fmaxf(acc[mf][nf][2] + bv.z, 0.f);
            float x3 = fmaxf(acc[mf][nf][3] + bv.w, 0.f);
            uint2 w;
            w.x = pk2bf(x0, x1);
            w.y = pk2bf(x2, x3);
            const int row = nf * 16 + lr;
            const int colbyte = (n0 + mf * 16 + kg * 4) << 1;
            *(uint2*)(ldsOut + row * 1024 + (colbyte ^ ((row & 7) << 4))) = w;
        }
    }
}

__global__ __launch_bounds__(256, 2) void fused_mlp(
    const uint16_t* __restrict__ Xbf,
    const uint16_t* __restrict__ W1T, const float* __restrict__ b1,
    const uint16_t* __restrict__ W2T, const float* __restrict__ b2,
    const uint16_t* __restrict__ W3T, const float* __restrict__ b3,
    float* __restrict__ out) {
    extern __shared__ char hbuf[];
    const int tid = threadIdx.x, wid = tid >> 6, lane = tid & 63;
    const int kg = lane >> 4, lr = lane & 15;
    const int e  = blockIdx.x & 7;
    const int b0 = (blockIdx.x >> 3) * 64;
    const int n0 = wid * 128;
    layer128<256, false>(W1T + ((size_t)e * 512 + n0) * 256, Xbf + (size_t)b0 * 256,
                         nullptr, b1 + e * 512 + n0, hbuf, n0, kg, lr, false);
    __syncthreads();
    layer128<512, true>(W2T + ((size_t)e * 512 + n0) * 512, nullptr, hbuf,
                        b2 + e * 512 + n0, hbuf, n0, kg, lr, true);
    __syncthreads();
    {
        const int rowB  = wid * 16 + lr;
        const int bbyte = rowB * 1024;
        const int bswz  = (rowB & 7) << 4;
        const uint16_t* W3e = W3T + (size_t)e * 32 * 512;
        f32x4 acc[2];
        acc[0] = f32x4{0.f, 0.f, 0.f, 0.f};
        acc[1] = f32x4{0.f, 0.f, 0.f, 0.f};
#pragma unroll
        for (int k0 = 0; k0 < 512; k0 += 32) {
            bf16x8 a = *(const bf16x8*)(hbuf + bbyte + ((((k0 + kg * 8) << 1)) ^ bswz));
#pragma unroll
            for (int nf = 0; nf < 2; ++nf) {
                bf16x8 b = *(const bf16x8*)(W3e + (size_t)(nf * 16 + lr) * 512 + k0 + kg * 8);
                acc[nf] = __builtin_amdgcn_mfma_f32_16x16x32_bf16(a, b, acc[nf], 0, 0, 0);
            }
        }
#pragma unroll
        for (int nf = 0; nf < 2; ++nf) {
            const float bb = b3[e * 32 + nf * 16 + lr];
#pragma unroll
            for (int v = 0; v < 4; ++v) {
                const int row = b0 + wid * 16 + kg * 4 + v;
                out[(size_t)row * 256 + e * 32 + nf * 16 + lr] = acc[nf][v] + bb;
            }
        }
    }
}

// ---------------- host launch ----------------
extern "C" void kernel_launch(void* const* d_in, const int* in_sizes, int n_in,
                              void* d_out, int out_size, void* d_ws, size_t ws_size,
                              hipStream_t stream) {
    (void)in_sizes; (void)n_in; (void)out_size;
    const float* X  = (const float*)d_in[0];   // [16384,256]
    const float* W1 = (const float*)d_in[1];   // [8,256,512]
    const float* b1 = (const float*)d_in[2];   // [8,512]
    const float* W2 = (const float*)d_in[3];   // [8,512,512]
    const float* b2 = (const float*)d_in[4];   // [8,512]
    const float* W3 = (const float*)d_in[5];   // [8,512,32]
    const float* b3 = (const float*)d_in[6];   // [8,32]
    float* out = (float*)d_out;                // [16384,8,32]

    uint16_t* w1t = (uint16_t*)d_ws;           // [8][512][256] bf16  (2 MB)
    uint16_t* w2t = w1t + 8 * 256 * 512;       // [8][512][512] bf16  (4 MB)
    uint16_t* w3t = w2t + 8 * 512 * 512;       // [8][32][512]  bf16  (256 KB)
    uint16_t* xbf = w3t + 8 * 512 * 32;        // [16384][256]  bf16  (8 MB)
    uint16_t* h1  = xbf + (size_t)16384 * 256; // [8][Mc][512] bf16, e-major
    const size_t FIXED_BYTES = ((size_t)(8 * 256 * 512) + 8 * 512 * 512 + 8 * 32 * 512 +
                                (size_t)16384 * 256) * 2;   // 14,942,208

    // largest chunk whose e-indexed h1+h2 fit the workspace
    int Mc = 0;
    for (int cand = 16384; cand >= 2048; cand >>= 1) {
        if (ws_size >= FIXED_BYTES + (size_t)16384 * cand) { Mc = cand; break; }
    }

    dim3 blk(32, 8);
    transpose_bf16<<<dim3(512 / 32, 256 / 32, 8), blk, 0, stream>>>(W1, w1t, 256, 512);
    transpose_bf16<<<dim3(512 / 32, 512 / 32, 8), blk, 0, stream>>>(W2, w2t, 512, 512);
    transpose_bf16<<<dim3(32 / 32, 512 / 32, 8),  blk, 0, stream>>>(W3, w3t, 512, 32);
    cvt_bf16<<<4096, 256, 0, stream>>>(X, xbf, 16384 * 256 / 4);

    if (Mc > 0) {
        uint16_t* h2 = h1 + (size_t)8 * Mc * 512;
        const size_t eStr = (size_t)Mc * 512;
        (void)hipFuncSetAttribute((const void*)gemm256<256>,
                                  hipFuncAttributeMaxDynamicSharedMemorySize, 131072);
        (void)hipFuncSetAttribute((const void*)gemm256<512>,
                                  hipFuncAttributeMaxDynamicSharedMemorySize, 131072);
        for (int c0 = 0; c0 < 16384; c0 += Mc) {
            gemm256<256><<<dim3(8, 2, Mc / 256), 512, 131072, stream>>>(
                xbf + (size_t)c0 * 256, 0, w1t, b1, h1, eStr);
            gemm256<512><<<dim3(8, 2, Mc / 256), 512, 131072, stream>>>(
                h1, eStr, w2t, b2, h2, eStr);
            gemm_o<<<dim3(8, 1, Mc / 128), 256, 0, stream>>>(
                h2, eStr, w3t, b3, out + (size_t)c0 * 256);
        }
    } else {
        (void)hipFuncSetAttribute((const void*)fused_mlp,
                                  hipFuncAttributeMaxDynamicSharedMemorySize, 65536);
        fused_mlp<<<2048, 256, 65536, stream>>>(xbf, w1t, b1, w2t, b2, w3t, b3, out);
    }
}